// Round 14
// baseline (84.583 us; speedup 1.0000x reference)
//
#include <hip/hip_runtime.h>

#define NG 48
#define NT 6                    // 4 A tiles per axis (8 cells)
#define NTILES (NT * NT * NT)   // 216
#define LCAP 1280               // compacted list capacity; hot tile ~1010

__device__ __forceinline__ float type_r(int type) {
    return (type == 0) ? 1.7f : ((type == 1) ? 1.55f : 1.52f);
}

// ONE kernel, ONE dispatch, zero cross-block communication.
// Block = (tile, type), 1024 threads (16 waves).
//   scan:    16 rounds of coalesced box tests over all atoms (L2-resident)
//   compact: deterministic ballot-ordered placement into LDS float4 list
//   eval:    thread owns 1 cell + half the list; wave-uniform x-plane cull;
//            halves combined via LDS; all 512 cells stored (zeros if empty)
__global__ __launch_bounds__(1024) void splat_one(
    const float* __restrict__ vC, const float* __restrict__ vN,
    const float* __restrict__ vO, float* __restrict__ out, int natoms)
{
    const int type = blockIdx.y;
    const int t    = blockIdx.x;
    const float r = type_r(type);
    const float* __restrict__ vecs = (type == 0) ? vC : ((type == 1) ? vN : vO);

    const int tx = t / (NT * NT);
    const int ty = (t / NT) % NT;
    const int tz = t % NT;

    const int tid  = threadIdx.x;
    const int wave = tid >> 6;
    const int lane = tid & 63;

    // tile acceptance box (superset of d < 1.5r support: cell centers span
    // [4T, 4T+3.5]; strict pad keeps the exact predicate d<1.5r inside)
    const float bb  = 1.5f * r + 1e-3f;
    const float lox = 4.0f * tx - bb, hix = 4.0f * tx + 3.5f + bb;
    const float loy = 4.0f * ty - bb, hiy = 4.0f * ty + 3.5f + bb;
    const float loz = 4.0f * tz - bb, hiz = 4.0f * tz + 3.5f + bb;

    __shared__ float4 sa[LCAP];
    __shared__ float  sacc[1024];
    __shared__ int    wtot[16];
    __shared__ int    wbase[17];

    // ---- scan: accept mask for this thread's 16 strided atoms ----
    unsigned int accept = 0u;
    const int nr = (natoms + 1023) >> 10;        // 16
    for (int k = 0; k < nr; ++k) {
        const int a = (k << 10) + tid;
        bool ok = false;
        if (a < natoms) {
            const float vx = vecs[3 * a + 0] + 23.5f;   // vec = raw + 24 - 0.5
            const float vy = vecs[3 * a + 1] + 23.5f;
            const float vz = vecs[3 * a + 2] + 23.5f;
            ok = (vx > lox) & (vx < hix) & (vy > loy) & (vy < hiy)
               & (vz > loz) & (vz < hiz);
        }
        accept |= (ok ? 1u : 0u) << k;
    }

    // ---- deterministic compaction: wave totals -> prefix -> placement ----
    int wcnt = 0;
    for (int k = 0; k < nr; ++k)
        wcnt += (int)__popcll(__ballot((accept >> k) & 1u));
    if (lane == 0) wtot[wave] = wcnt;
    __syncthreads();
    if (tid == 0) {
        int s = 0;
        #pragma unroll
        for (int w = 0; w < 16; ++w) { wbase[w] = s; s += wtot[w]; }
        wbase[16] = s;
    }
    __syncthreads();
    const int n = min(wbase[16], LCAP);

    int run = wbase[wave];
    for (int k = 0; k < nr; ++k) {
        const unsigned long long m = __ballot((accept >> k) & 1u);
        if ((accept >> k) & 1u) {
            const int pos = run + (int)__popcll(m & ((1ull << lane) - 1ull));
            if (pos < LCAP) {
                const int a = (k << 10) + tid;
                sa[pos] = make_float4(vecs[3 * a + 0] + 23.5f,
                                      vecs[3 * a + 1] + 23.5f,
                                      vecs[3 * a + 2] + 23.5f, 0.0f);
            }
        }
        run += (int)__popcll(m);
    }
    __syncthreads();

    // ---- eval: 1 cell/thread, half the list per h; wave = one x-plane ----
    const int cell = tid & 511;
    const int h    = tid >> 9;
    const int lx   = cell >> 6;
    const int ly   = (cell >> 3) & 7;
    const int lz   = cell & 7;

    const float r15sq = (1.5f * r) * (1.5f * r);   // exact predicate, no pad
    const float rr    = r * r;
    const float E2    = 7.3890562f;
    const float c2a   = 4.0f / (E2 * rr);
    const float c2b   = 12.0f / (E2 * r);
    const float c2c   = 9.0f / E2;
    const float n2orr = -2.0f / rr;

    const float px = 0.5f * (float)(tx * 8 + lx);
    const float py = 0.5f * (float)(ty * 8 + ly);
    const float pz = 0.5f * (float)(tz * 8 + lz);

    const int sz = (n + 1) >> 1;
    const int lo = h * sz;
    const int hi = min(n, lo + sz);

    float acc = 0.0f;
    for (int j = lo; j < hi; ++j) {
        const float4 a = sa[j];                 // b128 broadcast within wave
        const float dx  = a.x - px;             // identical across the wave
        const float dxx = dx * dx;
        if (dxx >= r15sq) continue;             // wave-uniform plane cull
        const float dy = a.y - py;
        const float dz = a.z - pz;
        const float d2 = fmaf(dy, dy, fmaf(dz, dz, dxx));
        const bool hit = d2 < r15sq;
        if (__ballot(hit) == 0ull) continue;    // whole-wave miss cull
        const float d   = sqrtf(d2);
        const float val = (d < r) ? __expf(n2orr * d2)
                                  : fmaf(c2a, d2, fmaf(-c2b, d, c2c));
        acc += hit ? val : 0.0f;
    }

    sacc[tid] = acc;
    __syncthreads();

    if (tid < 512) {
        const float o = sacc[tid] + sacc[tid + 512];   // fixed order: h0 + h1
        const int X = tx * 8 + lx;
        const int Y = ty * 8 + ly;
        const int Z = tz * 8 + lz;
        out[(size_t)type * NG * NG * NG + ((size_t)X * NG + Y) * NG + Z] = o;
    }
}

extern "C" void kernel_launch(void* const* d_in, const int* in_sizes, int n_in,
                              void* d_out, int out_size, void* d_ws, size_t ws_size,
                              hipStream_t stream) {
    const float* vC = (const float*)d_in[0];
    const float* vN = (const float*)d_in[1];
    const float* vO = (const float*)d_in[2];
    float* out = (float*)d_out;

    const int natoms = in_sizes[0] / 3;   // 16384

    dim3 grid(NTILES, 3, 1);
    splat_one<<<grid, 1024, 0, stream>>>(vC, vN, vO, out, natoms);
}

// Round 15
// 70.667 us; speedup vs baseline: 1.1969x; 1.1969x over previous
//
#include <hip/hip_runtime.h>

#define NG 48
#define NT 6                    // 4 A tiles per axis (8 cells)
#define NTILES (NT * NT * NT)   // 216
#define LCAP 1280               // compacted list capacity; hot tile ~1010

__device__ __forceinline__ float type_r(int type) {
    return (type == 0) ? 1.7f : ((type == 1) ? 1.55f : 1.52f);
}

// ONE dispatch, zero cross-block communication, LDS-issue-optimal eval:
// each wave covers the WHOLE 512-cell tile (lane=(bx,by,bz) in 4^3, thread
// owns cells base+{0,4}^3) -> ONE ds_read_b128 per (tile, atom) instead of
// R14's 16. Block = 512 threads = 8 waves; wave w takes 1/8 of the list.
__global__ __launch_bounds__(512) void splat_one(
    const float* __restrict__ vC, const float* __restrict__ vN,
    const float* __restrict__ vO, float* __restrict__ out, int natoms)
{
    const int type = blockIdx.y;
    const int t    = blockIdx.x;
    const float r = type_r(type);
    const float* __restrict__ vecs = (type == 0) ? vC : ((type == 1) ? vN : vO);

    const int tx = t / (NT * NT);
    const int ty = (t / NT) % NT;
    const int tz = t % NT;

    const int tid  = threadIdx.x;
    const int wave = tid >> 6;          // 0..7
    const int lane = tid & 63;

    // tile acceptance box (superset of the exact d<1.5r support)
    const float bb  = 1.5f * r + 1e-3f;
    const float lox = 4.0f * tx - bb, hix = 4.0f * tx + 3.5f + bb;
    const float loy = 4.0f * ty - bb, hiy = 4.0f * ty + 3.5f + bb;
    const float loz = 4.0f * tz - bb, hiz = 4.0f * tz + 3.5f + bb;

    __shared__ float4 sa[LCAP];
    __shared__ float  sacc[8 * 512];
    __shared__ int    wtot[8];
    __shared__ int    wbase[9];

    // ---- scan: accept mask over 32 strided rounds (atoms L2-resident) ----
    unsigned int accept = 0u;
    const int nr = (natoms + 511) >> 9;          // 32
    for (int k = 0; k < nr; ++k) {
        const int a = (k << 9) + tid;
        bool ok = false;
        if (a < natoms) {
            const float vx = vecs[3 * a + 0] + 23.5f;   // vec = raw + 24 - 0.5
            const float vy = vecs[3 * a + 1] + 23.5f;
            const float vz = vecs[3 * a + 2] + 23.5f;
            ok = (vx > lox) & (vx < hix) & (vy > loy) & (vy < hiy)
               & (vz > loz) & (vz < hiz);
        }
        accept |= (ok ? 1u : 0u) << k;
    }

    // ---- deterministic compaction: wave totals -> prefix -> placement ----
    int wcnt = 0;
    for (int k = 0; k < nr; ++k)
        wcnt += (int)__popcll(__ballot((accept >> k) & 1u));
    if (lane == 0) wtot[wave] = wcnt;
    __syncthreads();
    if (tid == 0) {
        int s = 0;
        #pragma unroll
        for (int w = 0; w < 8; ++w) { wbase[w] = s; s += wtot[w]; }
        wbase[8] = s;
    }
    __syncthreads();
    const int n = min(wbase[8], LCAP);

    int run = wbase[wave];
    for (int k = 0; k < nr; ++k) {
        const unsigned long long m = __ballot((accept >> k) & 1u);
        if ((accept >> k) & 1u) {
            const int pos = run + (int)__popcll(m & ((1ull << lane) - 1ull));
            if (pos < LCAP) {
                const int a = (k << 9) + tid;
                sa[pos] = make_float4(vecs[3 * a + 0] + 23.5f,
                                      vecs[3 * a + 1] + 23.5f,
                                      vecs[3 * a + 2] + 23.5f, 0.0f);
            }
        }
        run += (int)__popcll(m);
    }
    __syncthreads();

    // ---- eval: lane=(bx,by,bz) in 4^3; 8 cells/thread = base+{0,4}^3 ----
    const int bx = lane >> 4;
    const int by = (lane >> 2) & 3;
    const int bz = lane & 3;

    const float r15sq = (1.5f * r) * (1.5f * r);
    const float rr    = r * r;
    const float E2    = 7.3890562f;
    const float c2a   = 4.0f / (E2 * rr);
    const float c2b   = 12.0f / (E2 * r);
    const float c2c   = 9.0f / E2;
    const float n2orr = -2.0f / rr;

    const float px = 0.5f * (float)(tx * 8 + bx);
    const float py = 0.5f * (float)(ty * 8 + by);
    const float pz = 0.5f * (float)(tz * 8 + bz);

    const int sz = (n + 7) >> 3;
    const int lo = wave * sz;
    const int hi = min(n, lo + sz);

    float acc[2][2][2] = {{{0.f,0.f},{0.f,0.f}},{{0.f,0.f},{0.f,0.f}}};

    if (lo < hi) {
        float4 cur = sa[lo];
        for (int j = lo; j < hi; ++j) {
            const float4 nxt = sa[min(j + 1, hi - 1)];   // 1-ahead prefetch
            const float dx0 = cur.x - px, dx1 = dx0 - 2.0f;
            const float dy0 = cur.y - py, dy1 = dy0 - 2.0f;
            const float dz0 = cur.z - pz, dz1 = dz0 - 2.0f;
            const float sx0 = dx0 * dx0, sx1 = dx1 * dx1;
            const float sy0 = dy0 * dy0, sy1 = dy1 * dy1;
            const float sz0 = dz0 * dz0, sz1 = dz1 * dz1;
            const float syz00 = sy0 + sz0, syz01 = sy0 + sz1;
            const float syz10 = sy1 + sz0, syz11 = sy1 + sz1;
            #pragma unroll
            for (int i = 0; i < 2; ++i) {
                const float sx = i ? sx1 : sx0;
                #pragma unroll
                for (int jj = 0; jj < 2; ++jj) {
                    #pragma unroll
                    for (int k = 0; k < 2; ++k) {
                        const float syz = jj ? (k ? syz11 : syz10)
                                             : (k ? syz01 : syz00);
                        const float d2 = sx + syz;
                        if (d2 < r15sq) {                 // exec-masked slot
                            const float d = sqrtf(d2);
                            acc[i][jj][k] +=
                                (d < r) ? __expf(n2orr * d2)
                                        : fmaf(c2a, d2, fmaf(-c2b, d, c2c));
                        }
                    }
                }
            }
            cur = nxt;
        }
    }

    // ---- per-wave partials -> fixed-order combine -> store ----
    #pragma unroll
    for (int i = 0; i < 2; ++i)
        #pragma unroll
        for (int jj = 0; jj < 2; ++jj)
            #pragma unroll
            for (int k = 0; k < 2; ++k) {
                const int cid = (((bx + 4 * i) * 8) + (by + 4 * jj)) * 8
                                + (bz + 4 * k);
                sacc[wave * 512 + cid] = acc[i][jj][k];
            }
    __syncthreads();

    if (tid < 512) {
        float o = 0.0f;
        #pragma unroll
        for (int w = 0; w < 8; ++w) o += sacc[w * 512 + tid];  // fixed order
        const int cx = tid >> 6;
        const int cy = (tid >> 3) & 7;
        const int cz = tid & 7;
        const int X = tx * 8 + cx;
        const int Y = ty * 8 + cy;
        const int Z = tz * 8 + cz;
        out[(size_t)type * NG * NG * NG + ((size_t)X * NG + Y) * NG + Z] = o;
    }
}

extern "C" void kernel_launch(void* const* d_in, const int* in_sizes, int n_in,
                              void* d_out, int out_size, void* d_ws, size_t ws_size,
                              hipStream_t stream) {
    const float* vC = (const float*)d_in[0];
    const float* vN = (const float*)d_in[1];
    const float* vO = (const float*)d_in[2];
    float* out = (float*)d_out;

    const int natoms = in_sizes[0] / 3;   // 16384

    dim3 grid(NTILES, 3, 1);
    splat_one<<<grid, 512, 0, stream>>>(vC, vN, vO, out, natoms);
}

// Round 16
// 43.957 us; speedup vs baseline: 1.9242x; 1.6077x over previous
//
#include <hip/hip_runtime.h>

#define NG 48
#define NT 6                    // 4 A tiles per axis (8 cells)
#define NTILES (NT * NT * NT)   // 216
#define NSEG 8                  // atom-slice segments
#define SCAP 384                // per-(tile,segment) capacity; hot lambda ~126
// ws layout:
//   [0,     20736)  int actc[3*216*8]   (count per (tile,seg), stored always)
//   [32768, +10.6M) float copies[3*216][NSEG][512]
#define COPIES_OFF 32768

__device__ __forceinline__ float type_r(int type) {
    return (type == 0) ? 1.7f : ((type == 1) ? 1.55f : 1.52f);
}

// Dispatch 1: one 256-thread block per (segment, tile, type).
//  scan:    block box-tests ONLY its 2048-atom slice against its tile's halo
//           (atoms L2-resident; 8 coalesced rounds)
//  compact: deterministic ballot-ordered placement into LDS (wave prefix)
//  eval:    2 cells/thread (x, x+4), whole-wave miss cull (R13's proven loop)
//  store:   512 partials iff count>0; count stored unconditionally.
// No global atomics, no pre-zeroed memory, fully deterministic.
__global__ __launch_bounds__(256) void gather_scan(
    const float* __restrict__ vC, const float* __restrict__ vN,
    const float* __restrict__ vO, int* __restrict__ actc,
    float* __restrict__ copies, int natoms)
{
    const int type = blockIdx.y;
    const int s = blockIdx.x / NTILES;        // segment-major spread
    const int t = blockIdx.x - s * NTILES;
    const int lt = type * NTILES + t;
    const float r = type_r(type);
    const float* __restrict__ vecs = (type == 0) ? vC : ((type == 1) ? vN : vO);

    const int tx = t / (NT * NT);
    const int ty = (t / NT) % NT;
    const int tz = t % NT;

    const int tid  = threadIdx.x;
    const int wave = tid >> 6;                // 0..3
    const int lane = tid & 63;

    // tile acceptance box (superset of the exact d<1.5r support)
    const float bb  = 1.5f * r + 1e-3f;
    const float lox = 4.0f * tx - bb, hix = 4.0f * tx + 3.5f + bb;
    const float loy = 4.0f * ty - bb, hiy = 4.0f * ty + 3.5f + bb;
    const float loz = 4.0f * tz - bb, hiz = 4.0f * tz + 3.5f + bb;

    __shared__ float4 sa[SCAP];
    __shared__ int wtot[4];
    __shared__ int wbase[5];

    // ---- scan this block's atom slice: accept-bit per round ----
    const int slen = (natoms + NSEG - 1) / NSEG;     // 2048
    const int alo  = s * slen;
    const int ahi  = min(natoms, alo + slen);
    const int nr   = (ahi - alo + 255) >> 8;         // 8

    unsigned int accept = 0u;
    for (int k = 0; k < nr; ++k) {
        const int a = alo + (k << 8) + tid;
        bool ok = false;
        if (a < ahi) {
            const float vx = vecs[3 * a + 0] + 23.5f;   // vec = raw + 24 - 0.5
            const float vy = vecs[3 * a + 1] + 23.5f;
            const float vz = vecs[3 * a + 2] + 23.5f;
            ok = (vx > lox) & (vx < hix) & (vy > loy) & (vy < hiy)
               & (vz > loz) & (vz < hiz);
        }
        accept |= (ok ? 1u : 0u) << k;
    }

    // ---- deterministic compaction ----
    int wcnt = 0;
    for (int k = 0; k < nr; ++k)
        wcnt += (int)__popcll(__ballot((accept >> k) & 1u));
    if (lane == 0) wtot[wave] = wcnt;
    __syncthreads();
    if (tid == 0) {
        int acc = 0;
        #pragma unroll
        for (int w = 0; w < 4; ++w) { wbase[w] = acc; acc += wtot[w]; }
        wbase[4] = acc;
    }
    __syncthreads();
    const int n = min(wbase[4], SCAP);

    if (tid == 0) actc[lt * NSEG + s] = n;     // unconditional count store

    if (n == 0) return;                         // inactive: nothing else

    int run = wbase[wave];
    for (int k = 0; k < nr; ++k) {
        const unsigned long long m = __ballot((accept >> k) & 1u);
        if ((accept >> k) & 1u) {
            const int pos = run + (int)__popcll(m & ((1ull << lane) - 1ull));
            if (pos < SCAP) {
                const int a = alo + (k << 8) + tid;
                sa[pos] = make_float4(vecs[3 * a + 0] + 23.5f,
                                      vecs[3 * a + 1] + 23.5f,
                                      vecs[3 * a + 2] + 23.5f, 0.0f);
            }
        }
        run += (int)__popcll(m);
    }
    __syncthreads();

    // ---- eval: 2 cells/thread (x, x+4); whole-wave miss cull ----
    const int lx = tid >> 6;           // 0..3
    const int ly = (tid >> 3) & 7;
    const int lz = tid & 7;

    const float r15sq = (1.5f * r) * (1.5f * r);
    const float rr    = r * r;
    const float E2    = 7.3890562f;
    const float c2a   = 4.0f / (E2 * rr);
    const float c2b   = 12.0f / (E2 * r);
    const float c2c   = 9.0f / E2;
    const float n2orr = -2.0f / rr;

    const float px0 = 0.5f * (float)(tx * 8 + lx);
    const float px1 = px0 + 2.0f;
    const float py  = 0.5f * (float)(ty * 8 + ly);
    const float pz  = 0.5f * (float)(tz * 8 + lz);

    float acc0 = 0.0f, acc1 = 0.0f;

    for (int j = 0; j < n; ++j) {
        const float4 a = sa[j];               // one b128 LDS broadcast
        const float dy  = a.y - py;
        const float dz  = a.z - pz;
        const float syz = fmaf(dy, dy, dz * dz);
        const float dx0 = a.x - px0;
        const float d2a = fmaf(dx0, dx0, syz);
        const float dx1 = a.x - px1;
        const float d2b = fmaf(dx1, dx1, syz);
        const bool h0 = d2a < r15sq;
        const bool h1 = d2b < r15sq;
        if (__ballot(h0 | h1) == 0ull) continue;   // whole-wave miss cull
        if (h0) {
            const float d = sqrtf(d2a);
            acc0 += (d < r) ? __expf(n2orr * d2a)
                            : fmaf(c2a, d2a, fmaf(-c2b, d, c2c));
        }
        if (h1) {
            const float d = sqrtf(d2b);
            acc1 += (d < r) ? __expf(n2orr * d2b)
                            : fmaf(c2a, d2b, fmaf(-c2b, d, c2c));
        }
    }

    float* __restrict__ cp = copies + ((size_t)lt * NSEG + s) * 512;
    cp[tid]       = acc0;
    cp[tid + 256] = acc1;
}

// Dispatch 2: one block per (tile,type). Sum stored segments (count>0) in
// fixed order; write all 512 cells exactly once (zeros for inactive tiles).
__global__ __launch_bounds__(256) void reduce_kernel(
    const int* __restrict__ actc, const float* __restrict__ copies,
    float* __restrict__ out)
{
    const int type = blockIdx.y;
    const int t = blockIdx.x;
    const int lt = type * NTILES + t;
    const int tid = threadIdx.x;

    __shared__ int segn[NSEG];
    if (tid < NSEG) segn[tid] = actc[lt * NSEG + tid];
    __syncthreads();

    const float* __restrict__ cp = copies + ((size_t)lt * NSEG) * 512;
    float o0 = 0.0f, o1 = 0.0f;
    #pragma unroll
    for (int ss = 0; ss < NSEG; ++ss) {
        if (segn[ss] > 0) {
            o0 += cp[(size_t)ss * 512 + tid];
            o1 += cp[(size_t)ss * 512 + 256 + tid];
        }
    }

    const int tx = t / (NT * NT);
    const int ty = (t / NT) % NT;
    const int tz = t % NT;
    const int lx = tid >> 6;
    const int ly = (tid >> 3) & 7;
    const int lz = tid & 7;
    const int X0 = tx * 8 + lx;
    const int Y  = ty * 8 + ly;
    const int Z  = tz * 8 + lz;
    float* __restrict__ o = out + (size_t)type * NG * NG * NG;
    o[((X0      * NG) + Y) * NG + Z] = o0;
    o[(((X0 + 4) * NG) + Y) * NG + Z] = o1;
}

extern "C" void kernel_launch(void* const* d_in, const int* in_sizes, int n_in,
                              void* d_out, int out_size, void* d_ws, size_t ws_size,
                              hipStream_t stream) {
    const float* vC = (const float*)d_in[0];
    const float* vN = (const float*)d_in[1];
    const float* vO = (const float*)d_in[2];
    float* out = (float*)d_out;

    int* actc = (int*)d_ws;
    float* copies = (float*)((char*)d_ws + COPIES_OFF);

    const int natoms = in_sizes[0] / 3;   // 16384

    dim3 ggrid(NTILES * NSEG, 3, 1);
    gather_scan<<<ggrid, 256, 0, stream>>>(vC, vN, vO, actc, copies, natoms);

    dim3 rgrid(NTILES, 3, 1);
    reduce_kernel<<<rgrid, 256, 0, stream>>>(actc, copies, out);
}